// Round 5
// baseline (159.953 us; speedup 1.0000x reference)
//
#include <hip/hip_runtime.h>

// SymmetryControl: B=16, C=96, H=96, W=96 fp32.
// out[b,c,h,i] = num/den, 6 taps of the same 96-wide row, gated by sigmoid(s[b,:]).
//
// R9 theory: R4-R8 all plateau at 2.0-2.3 TB/s. R8 proved register prefetch can't
// go deep: 16 float3 loads need 48 result VGPRs but the kernel compiled to 44 ->
// the allocator sank loads into the consume loop (1-deep pipeline, full latency
// per pair). Fix: depth at ZERO register cost via global_load_lds (async DMA to
// LDS, the CDNA cp.async). R4's verified quarter-structure phase 2 + 4-deep DMA
// pipeline with counted vmcnt (never 0 in steady state) + raw s_barrier (no
// __syncthreads -> no vmcnt(0) drain). Steady state: 6 KB in flight per wave,
// ~108 KB/CU outstanding (~50x today's ~1-2 KB/wave).
//
// Pipeline safety: one barrier per tile. Per-wave order is
//   [iter t]: waitcnt(own DMA for tile t) ; s_barrier ; stage tile t+D-1 ; compute t
// Passing barrier(t) implies ALL waves finished compute(t-1) (rendezvous), so
// staging into buffer (t+D-1)%D == (t-1)%D is race-free. vmcnt-before-barrier
// makes every wave's DMA writes LDS-visible to every other wave's ds_reads.
//
// Known cost: LDS tile rows are 384 B (bank-aligned, stride 96 floats) -> 3-way
// bank conflict on phase-2 ds_reads. Can't pad: DMA destination must be linear.

#define WDIM 96
#define ROWS 16                    // rows per tile
#define TILE_FLOATS (ROWS * WDIM)  // 1536 floats = 6144 B
#define DD 4                       // pipeline depth (power of 2)
#define T_TILES 12                 // tiles per block (768 blocks = 3/CU, one-shot)
#define RPB 9216                   // rows per batch (C*H)

__device__ __forceinline__ void g2l16(const float* g, float* l) {
    // 16B-per-lane async global->LDS. LDS dest = wave-uniform base + lane*16 (HW).
    __builtin_amdgcn_global_load_lds(
        (const __attribute__((address_space(1))) void*)g,
        (__attribute__((address_space(3))) void*)l,
        16, 0, 0);
}

__global__ __launch_bounds__(384)
void symctl_kernel(const float* __restrict__ x,
                   const float* __restrict__ s,
                   const float* __restrict__ w,
                   float* __restrict__ out) {
    __shared__ float xb[DD][TILE_FLOATS];
    __shared__ float wb[DD][TILE_FLOATS];

    const int tid  = threadIdx.x;
    const int wv   = tid >> 6;          // wave id 0..5
    const int lane = tid & 63;

    // staging: wave wv covers floats [wv*256, wv*256+256) of each 1536-float tile
    const int chunk = wv * 256 + lane * 4;   // per-lane float offset (16B/lane)
    const float* ldsx_base = &xb[0][0] + wv * 256;   // wave-uniform dests
    const float* ldsw_base = &wb[0][0] + wv * 256;

    const int tile0 = blockIdx.x * T_TILES;

    // ---- prologue: stage tiles 0..DD-2 (6 DMA issues, zero VGPR cost) ----
#pragma unroll
    for (int d = 0; d < DD - 1; ++d) {
        const size_t gbase = (size_t)(tile0 + d) * TILE_FLOATS + chunk;
        g2l16(x + gbase, (float*)(ldsx_base + d * TILE_FLOATS));
        g2l16(w + gbase, (float*)(ldsw_base + d * TILE_FLOATS));
    }

    // ---- block-uniform sigmoid gates (192 rows/block, 9216 % 192 == 0) ----
    const int b = (tile0 * ROWS) / RPB;
    const float* sb = s + b * 5;
    const float sg0 = 1.0f / (1.0f + __expf(-sb[0]));
    const float sg1 = 1.0f / (1.0f + __expf(-sb[1]));
    const float sg2 = 1.0f / (1.0f + __expf(-sb[2]));
    const float sg3 = 1.0f / (1.0f + __expf(-sb[3]));
    const float sg4 = 1.0f / (1.0f + __expf(-sb[4]));

    // phase-2 mapping (verified R4): thread = (t24, ry), 4 outputs at i = 24q + r
    const int t24 = tid % 24;
    const int ry  = tid / 24;           // 0..15
    const int r   = t24;
    const int rm  = 23 - t24;

    for (int t = 0; t < T_TILES; ++t) {
        const int d = t & (DD - 1);

        // counted waits: steady state leaves 4 loads (2 tiles) in flight.
        if (t < T_TILES - 2)       asm volatile("s_waitcnt vmcnt(4)" ::: "memory");
        else if (t == T_TILES - 2) asm volatile("s_waitcnt vmcnt(2)" ::: "memory");
        else                       asm volatile("s_waitcnt vmcnt(0)" ::: "memory");
        __builtin_amdgcn_s_barrier();

        // ---- stage tile t+DD-1 into buffer (t-1)%DD (safe post-rendezvous) ----
        if (t + DD - 1 < T_TILES) {
            const int dn = (t + DD - 1) & (DD - 1);
            const size_t gbase = (size_t)(tile0 + t + DD - 1) * TILE_FLOATS + chunk;
            g2l16(x + gbase, (float*)(ldsx_base + dn * TILE_FLOATS));
            g2l16(w + gbase, (float*)(ldsw_base + dn * TILE_FLOATS));
        }

        // ---- compute tile t from buffer d ----
        const float* xr = &xb[d][ry * WDIM];
        const float* wr = &wb[d][ry * WDIM];

        float pq[4], aq[4], pP[4], aP[4];
#pragma unroll
        for (int q = 0; q < 4; ++q) {
            const float xq = xr[24 * q + r];
            const float wq = wr[24 * q + r];
            const float xm = xr[24 * q + rm];
            const float wm = wr[24 * q + rm];
            pq[q] = xq * wq;  aq[q] = wq;
            pP[q] = xm * wm;  aP[q] = wm;
        }

        float* orow = out + (size_t)((tile0 + t) * ROWS + ry) * WDIM + r;
#pragma unroll
        for (int q = 0; q < 4; ++q) {
            const int i1 = (q + 3) & 3;   // q-1
            const int i2 = (q + 2) & 3;   // q-2
            const int i3 = (q + 1) & 3;   // q-3
            const int i4 = (4 - q) & 3;   // -q
            const int i5 = (5 - q) & 3;   // 1-q

            float num = pq[q];
            num = fmaf(sg0, pq[i1], num);
            num = fmaf(sg1, pq[i2], num);
            num = fmaf(sg2, pq[i3], num);
            num = fmaf(sg3, pP[i4], num);
            num = fmaf(sg4, pP[i5], num);

            float den = aq[q];
            den = fmaf(sg0, aq[i1], den);
            den = fmaf(sg1, aq[i2], den);
            den = fmaf(sg2, aq[i3], den);
            den = fmaf(sg3, aP[i4], den);
            den = fmaf(sg4, aP[i5], den);

            orow[24 * q] = num * __builtin_amdgcn_rcpf(den);
        }
    }
}

extern "C" void kernel_launch(void* const* d_in, const int* in_sizes, int n_in,
                              void* d_out, int out_size, void* d_ws, size_t ws_size,
                              hipStream_t stream) {
    const float* x = (const float*)d_in[0];
    const float* s = (const float*)d_in[1];
    const float* w = (const float*)d_in[2];
    float* out = (float*)d_out;

    const int n_rows = in_sizes[0] / WDIM;              // 147456
    const int grid   = n_rows / (ROWS * T_TILES);       // 768 blocks (3/CU, one-shot)

    dim3 block(384);
    symctl_kernel<<<grid, block, 0, stream>>>(x, s, w, out);
}

// Round 6
// 152.117 us; speedup vs baseline: 1.0515x; 1.0515x over previous
//
#include <hip/hip_runtime.h>

// SymmetryControl: B=16, C=96, H=96, W=96 fp32.
// out[b,c,h,i] = num/den, 6 taps of the same 96-wide row, gated by sigmoid(s[b,:]).
//
// R10 theory: R1-R9 (six structures) all plateau at 2.0-2.3 TB/s. Invariant:
// per-wave pipeline depth ~1 — the register allocator sinks C-level prefetches
// (R7 VGPR=28, R8 VGPR=44 vs 48 needed), and the DMA variant traded depth for
// occupancy (20%) + bank conflicts. Exposed latency: ~1-2KB/wave in flight
// / ~900 cyc = 2.2 TB/s. Fix: loads as inline-asm (cannot be sunk/split/remat;
// asm volatile order is preserved), hand-counted descending vmcnt waits
// (12/8/4/0; loads retire in order, m135), sched_barrier(0) after each wait
// (rule #18: hipcc hoists reg-ops past asm waitcnt), stores deferred to the end
// so they never enter the vmcnt arithmetic. Zero LDS, zero barriers, bpermute
// gather (verified R6/R7). 4 row-pairs/wave one-shot = 6KB in flight per wave,
// ~16-32 waves/CU -> 100-200 KB/CU outstanding (~50-100x previous rounds).
//
// Row->lane map (verified R6/R7): row = 32 lanes x 3 floats, 2 rows/wave:
//   col i = 3*tl + e
//   shift -24: lane (tl-8)&31,  same elem
//   shift -48: lane (tl-16)&31, same elem
//   shift -72: lane (tl+8)&31,  same elem
//   flip 23-i: lane (7-tl)&31,  elems reversed
//   flip 47-i: lane (15-tl)&31, elems reversed

#define WDIM  96
#define RPB   9216           // rows per batch (C*H)
#define WPB   4              // waves per block (256 threads)
#define PAIRS 4              // row-pairs per wave (one-shot)
#define RPW   (2 * PAIRS)    // 8 rows per wave

typedef float v2f __attribute__((ext_vector_type(2)));

__device__ __forceinline__ float bperm(int byteidx, float v) {
    return __int_as_float(__builtin_amdgcn_ds_bpermute(byteidx, __float_as_int(v)));
}

__global__ __launch_bounds__(64 * WPB)
void symctl_kernel(const float* __restrict__ x,
                   const float* __restrict__ s,
                   const float* __restrict__ w,
                   float* __restrict__ out) {
    const int lane = threadIdx.x & 63;
    const int tl   = lane & 31;          // position within 32-lane half
    const int hsel = lane & 32;          // half selector (0 / 32)
    const int h    = lane >> 5;          // row parity within each pair

    const int wid  = blockIdx.x * WPB + (threadIdx.x >> 6);   // global wave id
    // lane handles rows RPW*wid + 2k + h, floats [3*tl, 3*tl+3)
    const int voff = ((RPW * wid + h) * WDIM + 3 * tl) * 4;   // byte offset, <2^31

    // ---- block-uniform sigmoid gates FIRST (scalar SMEM path, lgkmcnt only,
    //      never enters the vmcnt queue we hand-count below) ----
    const int b = (blockIdx.x * (RPW * WPB)) / RPB;           // block-uniform
    const float* sb = s + b * 5;
    const float sg0 = 1.0f / (1.0f + __expf(-sb[0]));
    const float sg1 = 1.0f / (1.0f + __expf(-sb[1]));
    const float sg2 = 1.0f / (1.0f + __expf(-sb[2]));
    const float sg3 = 1.0f / (1.0f + __expf(-sb[3]));
    const float sg4 = 1.0f / (1.0f + __expf(-sb[4]));

    // bpermute byte indices (per-lane constants, stay within own 32-lane half)
    const int i90  = (hsel | ((tl -  8) & 31)) << 2;
    const int i180 = (hsel | ((tl - 16) & 31)) << 2;
    const int i270 = (hsel | ((tl +  8) & 31)) << 2;
    const int f90  = (hsel | (( 7 - tl) & 31)) << 2;
    const int f180 = (hsel | ((15 - tl) & 31)) << 2;

    // ---- 16 inline-asm loads, issued back-to-back, cannot be sunk by RA ----
    // pair k: x[lo,hi], w[lo,hi] at byte offsets k*768 (+8 for hi dword)
    v2f   xlo0, xlo1, xlo2, xlo3, wlo0, wlo1, wlo2, wlo3;
    float xhi0, xhi1, xhi2, xhi3, whi0, whi1, whi2, whi3;
#define LD_PAIR(K, XLO, XHI, WLO, WHI)                                          \
    asm volatile("global_load_dwordx2 %0, %1, %2 offset:" #K                    \
                 : "=v"(XLO) : "v"(voff), "s"(x));                              \
    asm volatile("global_load_dword %0, %1, %2 offset:" #K "+8"                 \
                 : "=v"(XHI) : "v"(voff), "s"(x));                              \
    asm volatile("global_load_dwordx2 %0, %1, %2 offset:" #K                    \
                 : "=v"(WLO) : "v"(voff), "s"(w));                              \
    asm volatile("global_load_dword %0, %1, %2 offset:" #K "+8"                 \
                 : "=v"(WHI) : "v"(voff), "s"(w));
    LD_PAIR(0,    xlo0, xhi0, wlo0, whi0)
    LD_PAIR(768,  xlo1, xhi1, wlo1, whi1)
    LD_PAIR(1536, xlo2, xhi2, wlo2, whi2)
    LD_PAIR(2304, xlo3, xhi3, wlo3, whi3)
#undef LD_PAIR

    float o0x,o0y,o0z, o1x,o1y,o1z, o2x,o2y,o2z, o3x,o3y,o3z;

#define COMPUTE(XLO, XHI, WLO, WHI, OX, OY, OZ)                                 \
    {                                                                           \
        const float wcx = WLO.x, wcy = WLO.y, wcz = WHI;                        \
        const float p0 = XLO.x * wcx;                                           \
        const float p1 = XLO.y * wcy;                                           \
        const float p2 = XHI   * wcz;                                           \
        float n0 = p0, n1 = p1, n2 = p2;                                        \
        float d0 = wcx, d1 = wcy, d2 = wcz;                                     \
        n0 = fmaf(sg0, bperm(i90,  p0),  n0);                                   \
        n1 = fmaf(sg0, bperm(i90,  p1),  n1);                                   \
        n2 = fmaf(sg0, bperm(i90,  p2),  n2);                                   \
        d0 = fmaf(sg0, bperm(i90,  wcx), d0);                                   \
        d1 = fmaf(sg0, bperm(i90,  wcy), d1);                                   \
        d2 = fmaf(sg0, bperm(i90,  wcz), d2);                                   \
        n0 = fmaf(sg1, bperm(i180, p0),  n0);                                   \
        n1 = fmaf(sg1, bperm(i180, p1),  n1);                                   \
        n2 = fmaf(sg1, bperm(i180, p2),  n2);                                   \
        d0 = fmaf(sg1, bperm(i180, wcx), d0);                                   \
        d1 = fmaf(sg1, bperm(i180, wcy), d1);                                   \
        d2 = fmaf(sg1, bperm(i180, wcz), d2);                                   \
        n0 = fmaf(sg2, bperm(i270, p0),  n0);                                   \
        n1 = fmaf(sg2, bperm(i270, p1),  n1);                                   \
        n2 = fmaf(sg2, bperm(i270, p2),  n2);                                   \
        d0 = fmaf(sg2, bperm(i270, wcx), d0);                                   \
        d1 = fmaf(sg2, bperm(i270, wcy), d1);                                   \
        d2 = fmaf(sg2, bperm(i270, wcz), d2);                                   \
        n0 = fmaf(sg3, bperm(f90,  p2),  n0);                                   \
        n1 = fmaf(sg3, bperm(f90,  p1),  n1);                                   \
        n2 = fmaf(sg3, bperm(f90,  p0),  n2);                                   \
        d0 = fmaf(sg3, bperm(f90,  wcz), d0);                                   \
        d1 = fmaf(sg3, bperm(f90,  wcy), d1);                                   \
        d2 = fmaf(sg3, bperm(f90,  wcx), d2);                                   \
        n0 = fmaf(sg4, bperm(f180, p2),  n0);                                   \
        n1 = fmaf(sg4, bperm(f180, p1),  n1);                                   \
        n2 = fmaf(sg4, bperm(f180, p0),  n2);                                   \
        d0 = fmaf(sg4, bperm(f180, wcz), d0);                                   \
        d1 = fmaf(sg4, bperm(f180, wcy), d1);                                   \
        d2 = fmaf(sg4, bperm(f180, wcx), d2);                                   \
        OX = n0 * __builtin_amdgcn_rcpf(d0);                                    \
        OY = n1 * __builtin_amdgcn_rcpf(d1);                                    \
        OZ = n2 * __builtin_amdgcn_rcpf(d2);                                    \
    }

    // pair 0: 4 oldest loads retired (in-order retirement, m135)
    asm volatile("s_waitcnt vmcnt(12)" ::: "memory");
    __builtin_amdgcn_sched_barrier(0);
    COMPUTE(xlo0, xhi0, wlo0, whi0, o0x, o0y, o0z)

    asm volatile("s_waitcnt vmcnt(8)" ::: "memory");
    __builtin_amdgcn_sched_barrier(0);
    COMPUTE(xlo1, xhi1, wlo1, whi1, o1x, o1y, o1z)

    asm volatile("s_waitcnt vmcnt(4)" ::: "memory");
    __builtin_amdgcn_sched_barrier(0);
    COMPUTE(xlo2, xhi2, wlo2, whi2, o2x, o2y, o2z)

    asm volatile("s_waitcnt vmcnt(0)" ::: "memory");
    __builtin_amdgcn_sched_barrier(0);
    COMPUTE(xlo3, xhi3, wlo3, whi3, o3x, o3y, o3z)
#undef COMPUTE

    // ---- deferred stores (never pollute the hand-counted vmcnt queue) ----
    float* op = out + (voff >> 2);
    float3 o;
    o.x = o0x; o.y = o0y; o.z = o0z; *(float3*)(op + 0 * 2 * WDIM) = o;
    o.x = o1x; o.y = o1y; o.z = o1z; *(float3*)(op + 1 * 2 * WDIM) = o;
    o.x = o2x; o.y = o2y; o.z = o2z; *(float3*)(op + 2 * 2 * WDIM) = o;
    o.x = o3x; o.y = o3y; o.z = o3z; *(float3*)(op + 3 * 2 * WDIM) = o;
}

extern "C" void kernel_launch(void* const* d_in, const int* in_sizes, int n_in,
                              void* d_out, int out_size, void* d_ws, size_t ws_size,
                              hipStream_t stream) {
    const float* x = (const float*)d_in[0];
    const float* s = (const float*)d_in[1];
    const float* w = (const float*)d_in[2];
    float* out = (float*)d_out;

    const int n_rows = in_sizes[0] / WDIM;        // 147456 (in_sizes[0] = float count)
    const int waves  = n_rows / RPW;              // 18432
    const int grid   = waves / WPB;               // 4608 blocks of 256 threads

    dim3 block(64 * WPB);
    symctl_kernel<<<grid, block, 0, stream>>>(x, s, w, out);
}